// Round 8
// baseline (526.134 us; speedup 1.0000x reference)
//
#include <hip/hip_runtime.h>
#include <math.h>

#define NP 8192

using f32x4  = __attribute__((ext_vector_type(4))) float;
using bf16x8 = __attribute__((ext_vector_type(8))) short;

__device__ __forceinline__ unsigned short f2bf(float x) {
  unsigned int u = __float_as_uint(x);
  u = (u + 0x7FFFu + ((u >> 16) & 1u)) >> 16;
  return (unsigned short)u;
}
__device__ __forceinline__ float fast_log2(float x) { float r; asm("v_log_f32 %0, %1" : "=v"(r) : "v"(x)); return r; }
__device__ __forceinline__ float fast_exp2(float x) { float r; asm("v_exp_f32 %0, %1" : "=v"(r) : "v"(x)); return r; }
__device__ __forceinline__ float siluf(float x) { return x / (1.0f + expf(-x)); }
__device__ __forceinline__ float softplusf(float x) { return (x > 20.0f) ? x : log1pf(expf(x)); }
__device__ __forceinline__ float dot4(const float4 a, const float4 b) {
  return a.x * b.x + a.y * b.y + a.z * b.z + a.w * b.w;
}

// ws layout (bytes):
//   [36864,+32KB)  a[8192] f32   (a_j = 2*log2e*lw_j, no global shift needed)
//   [73728,+1MB)   Bt bf16[64][8192]  (state^T, row49=1, 50..63=0)

// ---------------- kernel 1: fused setup + per-particle transition + loglik ----
// 4 lanes cooperate per particle. Block = 128 thr = 32 particles, grid = 256.
__global__ __launch_bounds__(128) void k_particle(
    const float* __restrict__ rh,   const float* __restrict__ rlo,
    const float* __restrict__ z,    const float* __restrict__ rlog,
    const float* __restrict__ logw, const float* __restrict__ h_t,
    const float* __restrict__ obs_p,
    const float* __restrict__ eps_h, const float* __restrict__ eps_l,
    const float* __restrict__ embed,
    const float* __restrict__ W_rt1, const float* __restrict__ b_rt1,
    const float* __restrict__ W_rt2, const float* __restrict__ b_rt2,
    const float* __restrict__ W_d1,  const float* __restrict__ b_d1,
    const float* __restrict__ W_d2,  const float* __restrict__ b_d2,
    const float* __restrict__ W_d3,  const float* __restrict__ b_d3,
    const float* __restrict__ W_g,   const float* __restrict__ b_g,
    const float* __restrict__ W_c,   const float* __restrict__ b_c,
    const float* __restrict__ log_R, const float* __restrict__ log_obs_scale,
    const float* __restrict__ W_a1,  const float* __restrict__ b_a1,
    const float* __restrict__ W_a2,  const float* __restrict__ b_a2,
    float* __restrict__ a_out, unsigned short* __restrict__ Bt) {
  // compact weight tiles (h-columns dropped; folded into per-output consts)
  __shared__ float d1c[64 * 48];   // W_d1 cols 64..111
  __shared__ float gcs[32 * 48];   // W_g  cols 64..111
  __shared__ float ccs[32 * 48];   // W_c  cols 64..111
  __shared__ float rt1c[32 * 16];  // W_rt1 cols 64..79
  __shared__ float d2s[32 * 64];
  __shared__ float d3s[4 * 32];
  __shared__ float rt2s[5 * 32];
  __shared__ float embs[80];
  __shared__ float cD1[64], cRT1[32], cG[32], cC[32];
  __shared__ float bD2[32], bD3[4], bRT2[8];
  __shared__ float a1s[16], scal[8];  // scal: 0 alpha | 1 Rsrc | 2..6 scales
  // exchange buffers (padded strides to spread banks)
  __shared__ float x1ex[32 * 68];
  __shared__ float tx[32 * 36];
  __shared__ float stex[32 * 52];

  const int t = threadIdx.x;

#define STAGEM(DST, SRC, ROWS, SSTR, C0, NC)                          \
  for (int e = t; e < (ROWS) * (NC); e += 128) {                      \
    const int ro = e / (NC);                                          \
    const int co = e - ro * (NC);                                     \
    DST[e] = SRC[ro * (SSTR) + (C0) + co];                            \
  }
  STAGEM(d1c, W_d1, 64, 112, 64, 48)
  STAGEM(gcs, W_g, 32, 112, 64, 48)
  STAGEM(ccs, W_c, 32, 112, 64, 48)
  STAGEM(rt1c, W_rt1, 32, 80, 64, 16)
#undef STAGEM
  for (int e = t; e < 2048; e += 128) d2s[e] = W_d2[e];
  if (t < 128) d3s[t] = W_d3[t];
  for (int e = t; e < 160; e += 128) rt2s[e] = W_rt2[e];
  if (t < 80) embs[t] = embed[t];
  if (t < 32) bD2[t] = b_d2[t];
  if (t < 4)  bD3[t] = b_d3[t];
  if (t < 5)  bRT2[t] = b_rt2[t];

  // h-folded per-output constants (read W rows + h straight from global/L1)
  for (int o = t; o < 160; o += 128) {
    const float* wr; float bb;
    if (o < 64)       { wr = W_d1 + o * 112;        bb = b_d1[o]; }
    else if (o < 96)  { wr = W_rt1 + (o - 64) * 80; bb = b_rt1[o - 64]; }
    else if (o < 128) { wr = W_g + (o - 96) * 112;  bb = b_g[o - 96]; }
    else              { wr = W_c + (o - 128) * 112; bb = b_c[o - 128]; }
    float acc = bb;
    #pragma unroll
    for (int m = 0; m < 64; m += 4)
      acc += dot4(*(const float4*)(wr + m), *(const float4*)(h_t + m));
    if (o < 64) cD1[o] = acc;
    else if (o < 96) cRT1[o - 64] = acc;
    else if (o < 128) cG[o - 96] = acc;
    else cC[o - 128] = acc;
  }
  if (t < 16) {
    float acc = b_a1[t];
    #pragma unroll
    for (int m = 0; m < 64; m += 4)
      acc += dot4(*(const float4*)(W_a1 + t * 64 + m), *(const float4*)(h_t + m));
    a1s[t] = siluf(acc);
  } else if (t == 16) {
    scal[1] = fminf(fmaxf(expf(log_R[0]), 0.15f), 2.5f);
  } else if (t >= 17 && t < 22) {
    scal[2 + t - 17] = softplusf(log_obs_scale[t - 17]);
  }
  __syncthreads();  // B0
  if (t == 0) {
    float acc = b_a2[0];
    #pragma unroll
    for (int k = 0; k < 16; ++k) acc += W_a2[k] * a1s[k];
    scal[0] = acc;  // alpha (published by B1)
  }

  // ---------------- per-particle compute: 4 lanes per particle ----------
  const int l = t & 63, lbase = l & ~3;
  const int q = t >> 2, s = t & 3;
  const int j = blockIdx.x * 32 + q;
  const float obs = obs_p[0];

  float rlj[15];
  #pragma unroll
  for (int k = 0; k < 15; ++k) rlj[k] = rlog[j * 15 + k];
  float m0 = rlj[0];
  #pragma unroll
  for (int k = 1; k < 15; ++k) m0 = fmaxf(m0, rlj[k]);
  float sum = 0.0f, e5[5];
  #pragma unroll
  for (int k = 0; k < 15; ++k) { float e = expf(rlj[k] - m0); if (k < 5) e5[k] = e; sum += e; }
  const float inv = 1.0f / sum;

  float remb[16];
  #pragma unroll
  for (int c = 0; c < 16; ++c) {
    float acc = e5[0] * embs[c];
    #pragma unroll
    for (int k = 1; k < 5; ++k) acc += e5[k] * embs[k * 16 + c];
    remb[c] = acc * inv;
  }

  float zj[32];
  #pragma unroll
  for (int c = 0; c < 32; c += 4) {
    const float4 v = *(const float4*)(z + j * 32 + c);
    zj[c] = v.x; zj[c + 1] = v.y; zj[c + 2] = v.z; zj[c + 3] = v.w;
  }

  // regime-transition layer 1 (rows 4r+s)
  #pragma unroll
  for (int r = 0; r < 8; ++r) {
    const int o = 4 * r + s;
    float acc = cRT1[o];
    #pragma unroll
    for (int c = 0; c < 16; ++c) acc += rt1c[o * 16 + c] * remb[c];
    tx[q * 36 + o] = siluf(acc);
  }
  __syncthreads();  // B1
  float t1[32];
  #pragma unroll
  for (int c = 0; c < 32; c += 4) {
    const float4 v = *(const float4*)(tx + q * 36 + c);
    t1[c] = v.x; t1[c + 1] = v.y; t1[c + 2] = v.z; t1[c + 3] = v.w;
  }
  float updS = bRT2[s], upd4 = bRT2[4];
  #pragma unroll
  for (int c = 0; c < 32; ++c) { updS += rt2s[s * 32 + c] * t1[c]; upd4 += rt2s[128 + c] * t1[c]; }
  float nlg[15];
  #pragma unroll
  for (int k = 0; k < 4; ++k) nlg[k] = 0.7f * rlj[k] + 0.3f * __shfl(updS, lbase + k);
  nlg[4] = 0.7f * rlj[4] + 0.3f * upd4;
  #pragma unroll
  for (int k = 5; k < 15; ++k) nlg[k] = rlj[k];

  // dynamics layer 1 (rows 4r+s)
  #pragma unroll
  for (int r = 0; r < 16; ++r) {
    const int o = 4 * r + s;
    const float* wrow = d1c + o * 48;
    float acc = cD1[o];
    #pragma unroll
    for (int c = 0; c < 16; ++c) acc += wrow[c] * remb[c];
    #pragma unroll
    for (int c = 0; c < 32; ++c) acc += wrow[16 + c] * zj[c];
    x1ex[q * 68 + o] = siluf(acc);
  }
  __syncthreads();  // B2

  // dynamics layer 2 (rows 4r+s), x1 consumed in two register halves
  float acc8[8];
  #pragma unroll
  for (int r = 0; r < 8; ++r) acc8[r] = bD2[4 * r + s];
  #pragma unroll
  for (int half = 0; half < 2; ++half) {
    float xh[32];
    #pragma unroll
    for (int c = 0; c < 32; c += 4) {
      const float4 v = *(const float4*)(x1ex + q * 68 + half * 32 + c);
      xh[c] = v.x; xh[c + 1] = v.y; xh[c + 2] = v.z; xh[c + 3] = v.w;
    }
    #pragma unroll
    for (int r = 0; r < 8; ++r) {
      const int o = 4 * r + s;
      #pragma unroll
      for (int c = 0; c < 32; ++c) acc8[r] += d2s[o * 64 + half * 32 + c] * xh[c];
    }
  }
  #pragma unroll
  for (int r = 0; r < 8; ++r) tx[q * 36 + 4 * r + s] = siluf(acc8[r]);
  __syncthreads();  // B3
  float x2v[32];
  #pragma unroll
  for (int c = 0; c < 32; c += 4) {
    const float4 v = *(const float4*)(tx + q * 36 + c);
    x2v[c] = v.x; x2v[c + 1] = v.y; x2v[c + 2] = v.z; x2v[c + 3] = v.w;
  }
  float dps = bD3[s];
  #pragma unroll
  for (int c = 0; c < 32; ++c) dps += d3s[s * 32 + c] * x2v[c];
  const float dp0 = __shfl(dps, lbase), dp1 = __shfl(dps, lbase + 1);
  const float dp2 = __shfl(dps, lbase + 2), dp3 = __shfl(dps, lbase + 3);
  const float sig_h = softplusf(dp2) + 0.01f;
  const float sig_l = softplusf(dp3) + 0.01f;
  const float nh = fmaxf(rh[j] + dp0 + sig_h * eps_h[j], 0.0f);
  const float nl = fmaxf(rlo[j] + dp1 + sig_l * eps_l[j], 0.0f);

  // gate / candidate (rows 4r+s)
  #pragma unroll
  for (int r = 0; r < 8; ++r) {
    const int o = 4 * r + s;
    const float* gr = gcs + o * 48;
    const float* cr = ccs + o * 48;
    float ga = cG[o], caa = cC[o];
    #pragma unroll
    for (int c = 0; c < 16; ++c) { ga += gr[c] * remb[c]; caa += cr[c] * remb[c]; }
    #pragma unroll
    for (int c = 0; c < 32; ++c) { ga += gr[16 + c] * zj[c]; caa += cr[16 + c] * zj[c]; }
    const float gs = 1.0f / (1.0f + expf(-ga));
    stex[q * 52 + 2 + o] = gs * zj[o] + (1.0f - gs) * tanhf(caa);
  }

  if (s == 0) {
    stex[q * 52 + 0] = nh;
    stex[q * 52 + 1] = nl;
    #pragma unroll
    for (int k = 0; k < 15; ++k) stex[q * 52 + 34 + k] = nlg[k];
    // observation likelihood
    float m1 = nlg[0];
    #pragma unroll
    for (int k = 1; k < 15; ++k) m1 = fmaxf(m1, nlg[k]);
    float sum1 = 0.0f, e5b[5];
    #pragma unroll
    for (int k = 0; k < 15; ++k) { float e = expf(nlg[k] - m1); if (k < 5) e5b[k] = e; sum1 += e; }
    float dot = 0.0f;
    #pragma unroll
    for (int k = 0; k < 5; ++k) dot += e5b[k] * scal[2 + k];
    dot /= sum1;
    const float R  = fminf(fmaxf(scal[1] * dot, 0.15f), 4.0f);
    const float zz = (obs - nh) / R;
    const float xx = scal[0] * zz;
    float lcdf;
    if (xx > -6.0f) {
      double p = 0.5 * erfc(-(double)xx * 0.7071067811865475244);
      lcdf = (float)log(p);
    } else {
      const float ix2 = 1.0f / (xx * xx);
      const float ser = 1.0f + ix2 * (-1.0f + ix2 * (3.0f + ix2 * (-15.0f + ix2 * 105.0f)));
      lcdf = -0.5f * xx * xx - logf(-xx) - 0.918938533f + logf(ser);
    }
    const float loglik = 0.693147181f - logf(R) - 0.918938533f - 0.5f * zz * zz + lcdf;
    a_out[j] = (logw[j] + loglik) * 2.8853900817779268f;  // (1/tau)*log2(e)
  }
  __syncthreads();  // B4

  // transposed coalesced Bt write: thread t<64 owns row c=t
  if (t < 64) {
    const int c = t;
    const size_t base = (size_t)c * NP + (size_t)blockIdx.x * 32;
    if (c < 49) {
      #pragma unroll
      for (int e = 0; e < 4; ++e) {
        bf16x8 v8;
        #pragma unroll
        for (int r = 0; r < 8; ++r) v8[r] = (short)f2bf(stex[(8 * e + r) * 52 + c]);
        *(bf16x8*)(Bt + base + 8 * e) = v8;
      }
    } else if (c == 49) {
      bf16x8 v8;
      #pragma unroll
      for (int r = 0; r < 8; ++r) v8[r] = (short)0x3F80;
      #pragma unroll
      for (int e = 0; e < 4; ++e) *(bf16x8*)(Bt + base + 8 * e) = v8;
    } else {
      bf16x8 v8;
      #pragma unroll
      for (int r = 0; r < 8; ++r) v8[r] = 0;
      #pragma unroll
      for (int e = 0; e < 4; ++e) *(bf16x8*)(Bt + base + 8 * e) = v8;
    }
  }
}

// ---------------- kernel 2: fused gumbel-softmax @ state (MFMA) ----------------
// 8 waves/block, 8-way K-split (1024 cols per wave) -> 4096 waves = 4/SIMD.
__global__ __launch_bounds__(512) void k_resample(const float* __restrict__ u,
                                                  const float* __restrict__ a,
                                                  const unsigned short* __restrict__ Bt,
                                                  float* __restrict__ out) {
  __shared__ float cacc[8][64][16];
  __shared__ float zrow[16];
  const int t = threadIdx.x;
  const int w = t >> 6, l = t & 63;
  const int row = l & 15, kg = l >> 4;
  const int i0 = blockIdx.x << 4;
  const float* urow = u + (size_t)(i0 + row) * NP;
  const int jw = w << 10;  // 8-way K-split across waves

  f32x4 acc0 = {0.f, 0.f, 0.f, 0.f}, acc1 = acc0, acc2 = acc0, acc3 = acc0;

  #pragma unroll 2
  for (int kb = 0; kb < 32; ++kb) {
    const int jl = jw + (kb << 5) + (kg << 3);
    const float4 ua = *(const float4*)(urow + jl);
    const float4 ub = *(const float4*)(urow + jl + 4);
    const float4 aa = *(const float4*)(a + jl);
    const float4 ab = *(const float4*)(a + jl + 4);
    const float uu[8] = {ua.x, ua.y, ua.z, ua.w, ub.x, ub.y, ub.z, ub.w};
    const float av[8] = {aa.x, aa.y, aa.z, aa.w, ab.x, ab.y, ab.z, ab.w};
    bf16x8 af;
    #pragma unroll
    for (int e = 0; e < 8; ++e) {
      // w = exp((lw_j + g_ij)/tau) = exp2(a_j - 2*log2(-ln(u)+1e-10))
      const float t1 = fast_log2(uu[e] + 1e-10f);
      const float t2 = fmaf(t1, -0.69314718056f, 1e-10f);
      const float t3 = fast_log2(t2);
      const float wv = fast_exp2(fmaf(t3, -2.0f, av[e]));
      af[e] = (short)f2bf(wv);
    }
    const bf16x8 b0 = *(const bf16x8*)(Bt + ((0  + row) * NP + jl));
    const bf16x8 b1 = *(const bf16x8*)(Bt + ((16 + row) * NP + jl));
    const bf16x8 b2 = *(const bf16x8*)(Bt + ((32 + row) * NP + jl));
    const bf16x8 b3 = *(const bf16x8*)(Bt + ((48 + row) * NP + jl));
    acc0 = __builtin_amdgcn_mfma_f32_16x16x32_bf16(af, b0, acc0, 0, 0, 0);
    acc1 = __builtin_amdgcn_mfma_f32_16x16x32_bf16(af, b1, acc1, 0, 0, 0);
    acc2 = __builtin_amdgcn_mfma_f32_16x16x32_bf16(af, b2, acc2, 0, 0, 0);
    acc3 = __builtin_amdgcn_mfma_f32_16x16x32_bf16(af, b3, acc3, 0, 0, 0);
  }

  #pragma unroll
  for (int r = 0; r < 4; ++r) {
    cacc[w][l][0 * 4 + r] = acc0[r];
    cacc[w][l][1 * 4 + r] = acc1[r];
    cacc[w][l][2 * 4 + r] = acc2[r];
    cacc[w][l][3 * 4 + r] = acc3[r];
  }
  __syncthreads();

  // reduce 8 K-chunks; thread t -> col c = t&63, rows ((t>>6)*2 + rr)
  const int c = t & 63;
  float v[2];
  #pragma unroll
  for (int rr = 0; rr < 2; ++rr) {
    const int r    = ((t >> 6) << 1) + rr;
    const int lsrc = ((r >> 2) << 4) | (c & 15);
    const int reg  = ((c >> 4) << 2) + (r & 3);
    float sv = 0.0f;
    #pragma unroll
    for (int ww = 0; ww < 8; ++ww) sv += cacc[ww][lsrc][reg];
    v[rr] = sv;
    if (c == 49) zrow[r] = sv;  // ones-column = row normalizer Z_i
  }
  __syncthreads();
  if (c < 49) {
    #pragma unroll
    for (int rr = 0; rr < 2; ++rr) {
      const int r = ((t >> 6) << 1) + rr;
      out[(size_t)(i0 + r) * 49 + c] = v[rr] / zrow[r];
    }
  }
}

extern "C" void kernel_launch(void* const* d_in, const int* in_sizes, int n_in,
                              void* d_out, int out_size, void* d_ws, size_t ws_size,
                              hipStream_t stream) {
  const float* rh    = (const float*)d_in[0];
  const float* rlo   = (const float*)d_in[1];
  const float* z     = (const float*)d_in[2];
  const float* rlog  = (const float*)d_in[3];
  const float* logw  = (const float*)d_in[4];
  const float* h_t   = (const float*)d_in[5];
  const float* obs   = (const float*)d_in[6];
  const float* eps_h = (const float*)d_in[7];
  const float* eps_l = (const float*)d_in[8];
  const float* u     = (const float*)d_in[9];
  const float* embed = (const float*)d_in[10];
  const float* W_rt1 = (const float*)d_in[11];
  const float* b_rt1 = (const float*)d_in[12];
  const float* W_rt2 = (const float*)d_in[13];
  const float* b_rt2 = (const float*)d_in[14];
  const float* W_d1  = (const float*)d_in[15];
  const float* b_d1  = (const float*)d_in[16];
  const float* W_d2  = (const float*)d_in[17];
  const float* b_d2  = (const float*)d_in[18];
  const float* W_d3  = (const float*)d_in[19];
  const float* b_d3  = (const float*)d_in[20];
  const float* W_g   = (const float*)d_in[21];
  const float* b_g   = (const float*)d_in[22];
  const float* W_c   = (const float*)d_in[23];
  const float* b_c   = (const float*)d_in[24];
  const float* log_R = (const float*)d_in[25];
  const float* log_obs_scale = (const float*)d_in[26];
  const float* W_a1  = (const float*)d_in[27];
  const float* b_a1  = (const float*)d_in[28];
  const float* W_a2  = (const float*)d_in[29];
  const float* b_a2  = (const float*)d_in[30];

  float* ws_a = (float*)((char*)d_ws + 36864);
  unsigned short* ws_bt = (unsigned short*)((char*)d_ws + 73728);

  k_particle<<<256, 128, 0, stream>>>(rh, rlo, z, rlog, logw, h_t, obs, eps_h, eps_l,
                                      embed, W_rt1, b_rt1, W_rt2, b_rt2,
                                      W_d1, b_d1, W_d2, b_d2, W_d3, b_d3,
                                      W_g, b_g, W_c, b_c, log_R, log_obs_scale,
                                      W_a1, b_a1, W_a2, b_a2, ws_a, ws_bt);
  k_resample<<<512, 512, 0, stream>>>(u, ws_a, ws_bt, (float*)d_out);
}

// Round 9
// 468.871 us; speedup vs baseline: 1.1221x; 1.1221x over previous
//
#include <hip/hip_runtime.h>
#include <math.h>

#define NP 8192

using f32x4  = __attribute__((ext_vector_type(4))) float;
using bf16x8 = __attribute__((ext_vector_type(8))) short;

__device__ __forceinline__ unsigned short f2bf(float x) {
  unsigned int u = __float_as_uint(x);
  u = (u + 0x7FFFu + ((u >> 16) & 1u)) >> 16;
  return (unsigned short)u;
}
__device__ __forceinline__ float fast_log2(float x) { float r; asm("v_log_f32 %0, %1" : "=v"(r) : "v"(x)); return r; }
__device__ __forceinline__ float fast_exp2(float x) { float r; asm("v_exp_f32 %0, %1" : "=v"(r) : "v"(x)); return r; }
__device__ __forceinline__ float siluf(float x) { return x / (1.0f + expf(-x)); }
__device__ __forceinline__ float softplusf(float x) { return (x > 20.0f) ? x : log1pf(expf(x)); }
__device__ __forceinline__ float dot4(const float4 a, const float4 b) {
  return a.x * b.x + a.y * b.y + a.z * b.z + a.w * b.w;
}

// ws layout (bytes):
//   [36864,+32KB)  a[8192] f32   (a_j = 2*log2e*lw_j)
//   [73728,+1MB)   Bt2: bf16, layout [jblk=j>>5][b=c>>4][slot=kg*16+row][e=j&7]
//                  element (c,j): idx = (((j>>5)*4 + (c>>4))*64 + ((j>>3)&3)*16 + (c&15))*8 + (j&7)

// ---------------- kernel 1: fused setup + per-particle transition + loglik ----
__global__ __launch_bounds__(128) void k_particle(
    const float* __restrict__ rh,   const float* __restrict__ rlo,
    const float* __restrict__ z,    const float* __restrict__ rlog,
    const float* __restrict__ logw, const float* __restrict__ h_t,
    const float* __restrict__ obs_p,
    const float* __restrict__ eps_h, const float* __restrict__ eps_l,
    const float* __restrict__ embed,
    const float* __restrict__ W_rt1, const float* __restrict__ b_rt1,
    const float* __restrict__ W_rt2, const float* __restrict__ b_rt2,
    const float* __restrict__ W_d1,  const float* __restrict__ b_d1,
    const float* __restrict__ W_d2,  const float* __restrict__ b_d2,
    const float* __restrict__ W_d3,  const float* __restrict__ b_d3,
    const float* __restrict__ W_g,   const float* __restrict__ b_g,
    const float* __restrict__ W_c,   const float* __restrict__ b_c,
    const float* __restrict__ log_R, const float* __restrict__ log_obs_scale,
    const float* __restrict__ W_a1,  const float* __restrict__ b_a1,
    const float* __restrict__ W_a2,  const float* __restrict__ b_a2,
    float* __restrict__ a_out, unsigned short* __restrict__ Bt) {
  __shared__ float d1c[64 * 48];
  __shared__ float gcs[32 * 48];
  __shared__ float ccs[32 * 48];
  __shared__ float rt1c[32 * 16];
  __shared__ float d2s[32 * 64];
  __shared__ float d3s[4 * 32];
  __shared__ float rt2s[5 * 32];
  __shared__ float embs[80];
  __shared__ float cD1[64], cRT1[32], cG[32], cC[32];
  __shared__ float bD2[32], bD3[4], bRT2[8];
  __shared__ float a1s[16], scal[8];
  __shared__ float x1ex[32 * 68];
  __shared__ float tx[32 * 36];
  __shared__ float stex[32 * 52];

  const int t = threadIdx.x;

#define STAGEM(DST, SRC, ROWS, SSTR, C0, NC)                          \
  for (int e = t; e < (ROWS) * (NC); e += 128) {                      \
    const int ro = e / (NC);                                          \
    const int co = e - ro * (NC);                                     \
    DST[e] = SRC[ro * (SSTR) + (C0) + co];                            \
  }
  STAGEM(d1c, W_d1, 64, 112, 64, 48)
  STAGEM(gcs, W_g, 32, 112, 64, 48)
  STAGEM(ccs, W_c, 32, 112, 64, 48)
  STAGEM(rt1c, W_rt1, 32, 80, 64, 16)
#undef STAGEM
  for (int e = t; e < 2048; e += 128) d2s[e] = W_d2[e];
  if (t < 128) d3s[t] = W_d3[t];
  for (int e = t; e < 160; e += 128) rt2s[e] = W_rt2[e];
  if (t < 80) embs[t] = embed[t];
  if (t < 32) bD2[t] = b_d2[t];
  if (t < 4)  bD3[t] = b_d3[t];
  if (t < 5)  bRT2[t] = b_rt2[t];

  for (int o = t; o < 160; o += 128) {
    const float* wr; float bb;
    if (o < 64)       { wr = W_d1 + o * 112;        bb = b_d1[o]; }
    else if (o < 96)  { wr = W_rt1 + (o - 64) * 80; bb = b_rt1[o - 64]; }
    else if (o < 128) { wr = W_g + (o - 96) * 112;  bb = b_g[o - 96]; }
    else              { wr = W_c + (o - 128) * 112; bb = b_c[o - 128]; }
    float acc = bb;
    #pragma unroll
    for (int m = 0; m < 64; m += 4)
      acc += dot4(*(const float4*)(wr + m), *(const float4*)(h_t + m));
    if (o < 64) cD1[o] = acc;
    else if (o < 96) cRT1[o - 64] = acc;
    else if (o < 128) cG[o - 96] = acc;
    else cC[o - 128] = acc;
  }
  if (t < 16) {
    float acc = b_a1[t];
    #pragma unroll
    for (int m = 0; m < 64; m += 4)
      acc += dot4(*(const float4*)(W_a1 + t * 64 + m), *(const float4*)(h_t + m));
    a1s[t] = siluf(acc);
  } else if (t == 16) {
    scal[1] = fminf(fmaxf(expf(log_R[0]), 0.15f), 2.5f);
  } else if (t >= 17 && t < 22) {
    scal[2 + t - 17] = softplusf(log_obs_scale[t - 17]);
  }
  __syncthreads();  // B0
  if (t == 0) {
    float acc = b_a2[0];
    #pragma unroll
    for (int k = 0; k < 16; ++k) acc += W_a2[k] * a1s[k];
    scal[0] = acc;
  }

  const int l = t & 63, lbase = l & ~3;
  const int q = t >> 2, s = t & 3;
  const int j = blockIdx.x * 32 + q;
  const float obs = obs_p[0];

  float rlj[15];
  #pragma unroll
  for (int k = 0; k < 15; ++k) rlj[k] = rlog[j * 15 + k];
  float m0 = rlj[0];
  #pragma unroll
  for (int k = 1; k < 15; ++k) m0 = fmaxf(m0, rlj[k]);
  float sum = 0.0f, e5[5];
  #pragma unroll
  for (int k = 0; k < 15; ++k) { float e = expf(rlj[k] - m0); if (k < 5) e5[k] = e; sum += e; }
  const float inv = 1.0f / sum;

  float remb[16];
  #pragma unroll
  for (int c = 0; c < 16; ++c) {
    float acc = e5[0] * embs[c];
    #pragma unroll
    for (int k = 1; k < 5; ++k) acc += e5[k] * embs[k * 16 + c];
    remb[c] = acc * inv;
  }

  float zj[32];
  #pragma unroll
  for (int c = 0; c < 32; c += 4) {
    const float4 v = *(const float4*)(z + j * 32 + c);
    zj[c] = v.x; zj[c + 1] = v.y; zj[c + 2] = v.z; zj[c + 3] = v.w;
  }

  #pragma unroll
  for (int r = 0; r < 8; ++r) {
    const int o = 4 * r + s;
    float acc = cRT1[o];
    #pragma unroll
    for (int c = 0; c < 16; ++c) acc += rt1c[o * 16 + c] * remb[c];
    tx[q * 36 + o] = siluf(acc);
  }
  __syncthreads();  // B1
  float t1[32];
  #pragma unroll
  for (int c = 0; c < 32; c += 4) {
    const float4 v = *(const float4*)(tx + q * 36 + c);
    t1[c] = v.x; t1[c + 1] = v.y; t1[c + 2] = v.z; t1[c + 3] = v.w;
  }
  float updS = bRT2[s], upd4 = bRT2[4];
  #pragma unroll
  for (int c = 0; c < 32; ++c) { updS += rt2s[s * 32 + c] * t1[c]; upd4 += rt2s[128 + c] * t1[c]; }
  float nlg[15];
  #pragma unroll
  for (int k = 0; k < 4; ++k) nlg[k] = 0.7f * rlj[k] + 0.3f * __shfl(updS, lbase + k);
  nlg[4] = 0.7f * rlj[4] + 0.3f * upd4;
  #pragma unroll
  for (int k = 5; k < 15; ++k) nlg[k] = rlj[k];

  #pragma unroll
  for (int r = 0; r < 16; ++r) {
    const int o = 4 * r + s;
    const float* wrow = d1c + o * 48;
    float acc = cD1[o];
    #pragma unroll
    for (int c = 0; c < 16; ++c) acc += wrow[c] * remb[c];
    #pragma unroll
    for (int c = 0; c < 32; ++c) acc += wrow[16 + c] * zj[c];
    x1ex[q * 68 + o] = siluf(acc);
  }
  __syncthreads();  // B2

  float acc8[8];
  #pragma unroll
  for (int r = 0; r < 8; ++r) acc8[r] = bD2[4 * r + s];
  #pragma unroll
  for (int half = 0; half < 2; ++half) {
    float xh[32];
    #pragma unroll
    for (int c = 0; c < 32; c += 4) {
      const float4 v = *(const float4*)(x1ex + q * 68 + half * 32 + c);
      xh[c] = v.x; xh[c + 1] = v.y; xh[c + 2] = v.z; xh[c + 3] = v.w;
    }
    #pragma unroll
    for (int r = 0; r < 8; ++r) {
      const int o = 4 * r + s;
      #pragma unroll
      for (int c = 0; c < 32; ++c) acc8[r] += d2s[o * 64 + half * 32 + c] * xh[c];
    }
  }
  #pragma unroll
  for (int r = 0; r < 8; ++r) tx[q * 36 + 4 * r + s] = siluf(acc8[r]);
  __syncthreads();  // B3
  float x2v[32];
  #pragma unroll
  for (int c = 0; c < 32; c += 4) {
    const float4 v = *(const float4*)(tx + q * 36 + c);
    x2v[c] = v.x; x2v[c + 1] = v.y; x2v[c + 2] = v.z; x2v[c + 3] = v.w;
  }
  float dps = bD3[s];
  #pragma unroll
  for (int c = 0; c < 32; ++c) dps += d3s[s * 32 + c] * x2v[c];
  const float dp0 = __shfl(dps, lbase), dp1 = __shfl(dps, lbase + 1);
  const float dp2 = __shfl(dps, lbase + 2), dp3 = __shfl(dps, lbase + 3);
  const float sig_h = softplusf(dp2) + 0.01f;
  const float sig_l = softplusf(dp3) + 0.01f;
  const float nh = fmaxf(rh[j] + dp0 + sig_h * eps_h[j], 0.0f);
  const float nl = fmaxf(rlo[j] + dp1 + sig_l * eps_l[j], 0.0f);

  #pragma unroll
  for (int r = 0; r < 8; ++r) {
    const int o = 4 * r + s;
    const float* gr = gcs + o * 48;
    const float* cr = ccs + o * 48;
    float ga = cG[o], caa = cC[o];
    #pragma unroll
    for (int c = 0; c < 16; ++c) { ga += gr[c] * remb[c]; caa += cr[c] * remb[c]; }
    #pragma unroll
    for (int c = 0; c < 32; ++c) { ga += gr[16 + c] * zj[c]; caa += cr[16 + c] * zj[c]; }
    const float gs = 1.0f / (1.0f + expf(-ga));
    stex[q * 52 + 2 + o] = gs * zj[o] + (1.0f - gs) * tanhf(caa);
  }

  if (s == 0) {
    stex[q * 52 + 0] = nh;
    stex[q * 52 + 1] = nl;
    #pragma unroll
    for (int k = 0; k < 15; ++k) stex[q * 52 + 34 + k] = nlg[k];
    float m1 = nlg[0];
    #pragma unroll
    for (int k = 1; k < 15; ++k) m1 = fmaxf(m1, nlg[k]);
    float sum1 = 0.0f, e5b[5];
    #pragma unroll
    for (int k = 0; k < 15; ++k) { float e = expf(nlg[k] - m1); if (k < 5) e5b[k] = e; sum1 += e; }
    float dot = 0.0f;
    #pragma unroll
    for (int k = 0; k < 5; ++k) dot += e5b[k] * scal[2 + k];
    dot /= sum1;
    const float R  = fminf(fmaxf(scal[1] * dot, 0.15f), 4.0f);
    const float zz = (obs - nh) / R;
    const float xx = scal[0] * zz;
    float lcdf;
    if (xx > -6.0f) {
      double p = 0.5 * erfc(-(double)xx * 0.7071067811865475244);
      lcdf = (float)log(p);
    } else {
      const float ix2 = 1.0f / (xx * xx);
      const float ser = 1.0f + ix2 * (-1.0f + ix2 * (3.0f + ix2 * (-15.0f + ix2 * 105.0f)));
      lcdf = -0.5f * xx * xx - logf(-xx) - 0.918938533f + logf(ser);
    }
    const float loglik = 0.693147181f - logf(R) - 0.918938533f - 0.5f * zz * zz + lcdf;
    a_out[j] = (logw[j] + loglik) * 2.8853900817779268f;  // (1/tau)*log2(e)
  }
  __syncthreads();  // B4

  // Bt2 write: thread c owns state-row c; fragment-native layout, 16B stores.
  if (t < 64) {
    const int c = t;
    const int b = c >> 4, rowc = c & 15;
    if (c < 49) {
      #pragma unroll
      for (int m = 0; m < 4; ++m) {
        bf16x8 v8;
        #pragma unroll
        for (int r = 0; r < 8; ++r) v8[r] = (short)f2bf(stex[(8 * m + r) * 52 + c]);
        *(bf16x8*)(Bt + (size_t)(((blockIdx.x * 4 + b) * 64) + m * 16 + rowc) * 8) = v8;
      }
    } else if (c == 49) {
      bf16x8 v8;
      #pragma unroll
      for (int r = 0; r < 8; ++r) v8[r] = (short)0x3F80;
      #pragma unroll
      for (int m = 0; m < 4; ++m)
        *(bf16x8*)(Bt + (size_t)(((blockIdx.x * 4 + b) * 64) + m * 16 + rowc) * 8) = v8;
    } else {
      bf16x8 v8;
      #pragma unroll
      for (int r = 0; r < 8; ++r) v8[r] = 0;
      #pragma unroll
      for (int m = 0; m < 4; ++m)
        *(bf16x8*)(Bt + (size_t)(((blockIdx.x * 4 + b) * 64) + m * 16 + rowc) * 8) = v8;
    }
  }
}

// ---------------- kernel 2: fused gumbel-softmax @ state (MFMA, LDS-staged) ----
// Block: 512 thr (8 waves), 16 output rows. u tile 16x1024 staged per chunk with
// coalesced loads; transform+a-fold at staging; A-frags via ds_read_b128;
// B-frags via fully-contiguous Bt2 loads. 8 chunks; wave w does kb=w*4..+4/chunk.
#define WSTR 1032  // bf16 elems per LDS row (1024 + 8 pad -> 2-way banks, 16B aligned)
__global__ __launch_bounds__(512) void k_resample(const float* __restrict__ u,
                                                  const float* __restrict__ a,
                                                  const unsigned short* __restrict__ Bt,
                                                  float* __restrict__ out) {
  __shared__ unsigned short Wlds[16 * WSTR];
  __shared__ float cacc[8][64][16];
  __shared__ float zrow[16];
  const int t = threadIdx.x;
  const int w = t >> 6, l = t & 63;
  const int i0 = blockIdx.x << 4;

  f32x4 acc0 = {0.f, 0.f, 0.f, 0.f}, acc1 = acc0, acc2 = acc0, acc3 = acc0;

  for (int chunk = 0; chunk < 8; ++chunk) {
    const int c0 = chunk << 10;
    // ---- stage 16x1024 u-tile -> bf16 weights in LDS (coalesced) ----
    #pragma unroll
    for (int p = 0; p < 4; ++p) {
      const int fidx = (p << 12) + (t << 3);
      const int rr = fidx >> 10, col = fidx & 1023;
      const float* up = u + (size_t)(i0 + rr) * NP + c0 + col;
      const float4 ua = *(const float4*)(up);
      const float4 ub = *(const float4*)(up + 4);
      const float4 aa = *(const float4*)(a + c0 + col);
      const float4 ab = *(const float4*)(a + c0 + col + 4);
      const float uu[8] = {ua.x, ua.y, ua.z, ua.w, ub.x, ub.y, ub.z, ub.w};
      const float av[8] = {aa.x, aa.y, aa.z, aa.w, ab.x, ab.y, ab.z, ab.w};
      bf16x8 wv8;
      #pragma unroll
      for (int e = 0; e < 8; ++e) {
        // w = exp((lw_j + g_ij)/tau) = exp2(a_j - 2*log2(-ln(u)+1e-10))
        const float t1 = fast_log2(uu[e] + 1e-10f);
        const float t2 = fmaf(t1, -0.69314718056f, 1e-10f);
        const float t3 = fast_log2(t2);
        const float wv = fast_exp2(fmaf(t3, -2.0f, av[e]));
        wv8[e] = (short)f2bf(wv);
      }
      *(bf16x8*)(&Wlds[rr * WSTR + col]) = wv8;
    }
    __syncthreads();
    // ---- MFMA over this chunk: wave w handles kb = w*4 .. w*4+3 ----
    #pragma unroll
    for (int it = 0; it < 4; ++it) {
      const int kb   = (w << 2) + it;          // 0..31 within chunk
      const int jblk = (c0 >> 5) + kb;         // global 32-col block index
      const bf16x8 af = *(const bf16x8*)(&Wlds[(l & 15) * WSTR + (kb << 5) + ((l >> 4) << 3)]);
      const unsigned short* bp = Bt + (size_t)(jblk << 2) * 512;   // (jblk*4)*64*8
      const bf16x8 b0 = *(const bf16x8*)(bp + (0 * 64 + l) * 8);
      const bf16x8 b1 = *(const bf16x8*)(bp + (1 * 64 + l) * 8);
      const bf16x8 b2 = *(const bf16x8*)(bp + (2 * 64 + l) * 8);
      const bf16x8 b3 = *(const bf16x8*)(bp + (3 * 64 + l) * 8);
      acc0 = __builtin_amdgcn_mfma_f32_16x16x32_bf16(af, b0, acc0, 0, 0, 0);
      acc1 = __builtin_amdgcn_mfma_f32_16x16x32_bf16(af, b1, acc1, 0, 0, 0);
      acc2 = __builtin_amdgcn_mfma_f32_16x16x32_bf16(af, b2, acc2, 0, 0, 0);
      acc3 = __builtin_amdgcn_mfma_f32_16x16x32_bf16(af, b3, acc3, 0, 0, 0);
    }
    __syncthreads();
  }

  #pragma unroll
  for (int r = 0; r < 4; ++r) {
    cacc[w][l][0 * 4 + r] = acc0[r];
    cacc[w][l][1 * 4 + r] = acc1[r];
    cacc[w][l][2 * 4 + r] = acc2[r];
    cacc[w][l][3 * 4 + r] = acc3[r];
  }
  __syncthreads();

  // reduce 8 K-chunks; thread t -> col c = t&63, rows ((t>>6)*2 + rr)
  const int c = t & 63;
  float v[2];
  #pragma unroll
  for (int rr = 0; rr < 2; ++rr) {
    const int r    = ((t >> 6) << 1) + rr;
    const int lsrc = ((r >> 2) << 4) | (c & 15);
    const int reg  = ((c >> 4) << 2) + (r & 3);
    float sv = 0.0f;
    #pragma unroll
    for (int ww = 0; ww < 8; ++ww) sv += cacc[ww][lsrc][reg];
    v[rr] = sv;
    if (c == 49) zrow[r] = sv;  // ones-column = row normalizer Z_i
  }
  __syncthreads();
  if (c < 49) {
    #pragma unroll
    for (int rr = 0; rr < 2; ++rr) {
      const int r = ((t >> 6) << 1) + rr;
      out[(size_t)(i0 + r) * 49 + c] = v[rr] / zrow[r];
    }
  }
}

extern "C" void kernel_launch(void* const* d_in, const int* in_sizes, int n_in,
                              void* d_out, int out_size, void* d_ws, size_t ws_size,
                              hipStream_t stream) {
  const float* rh    = (const float*)d_in[0];
  const float* rlo   = (const float*)d_in[1];
  const float* z     = (const float*)d_in[2];
  const float* rlog  = (const float*)d_in[3];
  const float* logw  = (const float*)d_in[4];
  const float* h_t   = (const float*)d_in[5];
  const float* obs   = (const float*)d_in[6];
  const float* eps_h = (const float*)d_in[7];
  const float* eps_l = (const float*)d_in[8];
  const float* u     = (const float*)d_in[9];
  const float* embed = (const float*)d_in[10];
  const float* W_rt1 = (const float*)d_in[11];
  const float* b_rt1 = (const float*)d_in[12];
  const float* W_rt2 = (const float*)d_in[13];
  const float* b_rt2 = (const float*)d_in[14];
  const float* W_d1  = (const float*)d_in[15];
  const float* b_d1  = (const float*)d_in[16];
  const float* W_d2  = (const float*)d_in[17];
  const float* b_d2  = (const float*)d_in[18];
  const float* W_d3  = (const float*)d_in[19];
  const float* b_d3  = (const float*)d_in[20];
  const float* W_g   = (const float*)d_in[21];
  const float* b_g   = (const float*)d_in[22];
  const float* W_c   = (const float*)d_in[23];
  const float* b_c   = (const float*)d_in[24];
  const float* log_R = (const float*)d_in[25];
  const float* log_obs_scale = (const float*)d_in[26];
  const float* W_a1  = (const float*)d_in[27];
  const float* b_a1  = (const float*)d_in[28];
  const float* W_a2  = (const float*)d_in[29];
  const float* b_a2  = (const float*)d_in[30];

  float* ws_a = (float*)((char*)d_ws + 36864);
  unsigned short* ws_bt = (unsigned short*)((char*)d_ws + 73728);

  k_particle<<<256, 128, 0, stream>>>(rh, rlo, z, rlog, logw, h_t, obs, eps_h, eps_l,
                                      embed, W_rt1, b_rt1, W_rt2, b_rt2,
                                      W_d1, b_d1, W_d2, b_d2, W_d3, b_d3,
                                      W_g, b_g, W_c, b_c, log_R, log_obs_scale,
                                      W_a1, b_a1, W_a2, b_a2, ws_a, ws_bt);
  k_resample<<<512, 512, 0, stream>>>(u, ws_a, ws_bt, (float*)d_out);
}